// Round 6
// baseline (122.642 us; speedup 1.0000x reference)
//
#include <hip/hip_runtime.h>

// Problem constants: B=4096, I=30000, O=10000, I == 3*O.
// Flat identity: out-flat o covers x-flat [3o,3o+3); rows never break groups
// (30000 = 12*2500). So the op is a flat 3:1 banded reduction over B*I floats
// with w/bias indices periodic (7500 f4 / 2500 f4 per row).
#define BATCH 4096
#define INF   30000
#define OUTF  10000

#define THREADS       256
#define F4_PER_TILE   768
#define TILES_PER_BLK 2
#define F4_PER_BLK    (F4_PER_TILE * TILES_PER_BLK)          // 1536
#define NBLOCKS       ((BATCH * (INF / 4)) / F4_PER_BLK)     // 20000 exactly

typedef float f32x4 __attribute__((ext_vector_type(4)));

// ---------------------------------------------------------------------------
// Kernel 1: gather the active diagonal band of weight into workspace.
// w_band[i] = weight[i/3, i]  (flat: (i/3)*INF + i), i in [0, INF)
// ---------------------------------------------------------------------------
__global__ void gather_band_kernel(const float* __restrict__ weight,
                                   float* __restrict__ w_band) {
    int i = blockIdx.x * blockDim.x + threadIdx.x;
    if (i < INF) {
        int row = i / 3;
        w_band[i] = weight[(size_t)row * INF + i];
    }
}

// ---------------------------------------------------------------------------
// Kernel 2: flat banded reduction, copy-shaped memory access.
// Phase-split issue: all 6 nontemporal HBM x-loads issued first (96B/lane in
// flight), then 6 L2-hot w-loads, then FMA + LDS staging, one barrier,
// combine + bias, nontemporal coalesced store (evict-first: keeps the write
// stream from thrashing L2 where w_band lives).
//   phase 0: p0=d0+d1+d2, p1=d3
//   phase 1: p0=d0+d1,    p1=d2+d3
//   phase 2: p0=d0,       p1=d1+d2+d3
//   o.x=P0[3m]; o.y=P1[3m]+P0[3m+1]; o.z=P1[3m+1]+P0[3m+2]; o.w=P1[3m+2]
// ---------------------------------------------------------------------------
__global__ __launch_bounds__(THREADS)
void banded_flat_kernel(const float* __restrict__ x,
                        const float* __restrict__ w_band,
                        const float* __restrict__ bias,
                        float* __restrict__ out) {
    __shared__ float P0[F4_PER_BLK];   // 6 KB
    __shared__ float P1[F4_PER_BLK];   // 6 KB

    const int i = threadIdx.x;
    const unsigned b = blockIdx.x;
    const unsigned base = b * (unsigned)F4_PER_BLK;        // f4 index, fits u32
    const unsigned basemod_w = base % 7500u;               // uniform, once
    const unsigned basemod_b = (b * 512u) % 2500u;         // uniform, once

    const f32x4* xv4 = reinterpret_cast<const f32x4*>(x);
    const f32x4* wv4 = reinterpret_cast<const f32x4*>(w_band);   // 7500 f4

    // ---- phase A: issue ALL long-latency HBM loads first -------------------
    f32x4 xr[6];
    #pragma unroll
    for (int c = 0; c < 6; ++c) {
        const int k = i + c * THREADS;
        xr[c] = __builtin_nontemporal_load(xv4 + (size_t)(base + k));
    }

    // ---- phase B: L2-hot w loads -------------------------------------------
    f32x4 wr[6];
    #pragma unroll
    for (int c = 0; c < 6; ++c) {
        const int k = i + c * THREADS;
        unsigned wi = basemod_w + (unsigned)k;
        if (wi >= 7500u) wi -= 7500u;
        wr[c] = wv4[wi];
    }

    // ---- phase C: reduce to partial pairs, stage in LDS (SoA, no conflicts)
    #pragma unroll
    for (int c = 0; c < 6; ++c) {
        const int k = i + c * THREADS;
        const float d0 = xr[c].x * wr[c].x;
        const float d1 = xr[c].y * wr[c].y;
        const float d2 = xr[c].z * wr[c].z;
        const float d3 = xr[c].w * wr[c].w;

        // phase = (base+k) % 3 = (i+c) % 3   (1536%3==0, 256%3==1)
        const int ph = (i + c) % 3;
        P0[k] = d0 + (ph <= 1 ? d1 : 0.f) + (ph == 0 ? d2 : 0.f);
        P1[k] = d3 + (ph >= 1 ? d2 : 0.f) + (ph == 2 ? d1 : 0.f);
    }

    __syncthreads();

    // ---- phase D: combine, add bias, evict-first store ---------------------
    #pragma unroll
    for (int c2 = 0; c2 < 2; ++c2) {
        const int m = i + c2 * THREADS;                    // 0..511
        unsigned bi = basemod_b + (unsigned)m;
        if (bi >= 2500u) bi -= 2500u;
        const f32x4 bb = reinterpret_cast<const f32x4*>(bias)[bi];

        f32x4 o;
        o.x = P0[3*m]               + bb.x;
        o.y = P1[3*m]   + P0[3*m+1] + bb.y;
        o.z = P1[3*m+1] + P0[3*m+2] + bb.z;
        o.w = P1[3*m+2]             + bb.w;

        const unsigned G = b * 512u + (unsigned)m;         // output f4 index
        __builtin_nontemporal_store(o, reinterpret_cast<f32x4*>(out) + (size_t)G);
    }
}

extern "C" void kernel_launch(void* const* d_in, const int* in_sizes, int n_in,
                              void* d_out, int out_size, void* d_ws, size_t ws_size,
                              hipStream_t stream) {
    const float* x      = (const float*)d_in[0];   // [B, I]
    const float* weight = (const float*)d_in[1];   // [O, I]
    const float* bias   = (const float*)d_in[2];   // [O]
    float* out          = (float*)d_out;           // [B, O]
    float* w_band       = (float*)d_ws;            // INF floats = 120 KB

    // 1) gather band (30000 elements)
    {
        int threads = 256;
        int blocks = (INF + threads - 1) / threads;
        gather_band_kernel<<<blocks, threads, 0, stream>>>(weight, w_band);
    }

    // 2) flat banded reduction: 20000 blocks x 256 threads
    banded_flat_kernel<<<NBLOCKS, THREADS, 0, stream>>>(x, w_band, bias, out);
}